// Round 10
// baseline (75.607 us; speedup 1.0000x reference)
//
#include <hip/hip_runtime.h>
#include <math.h>

// 10-qubit real-amplitude circuit simulator, batch 16384, depth 8.
// Layout: 32 lanes per batch element (index bits [4:0] = lane&31),
//         16 x v2f (=32 scalars) per lane; scalar s = u*2 + comp.
// Qubit map: q0..q3 -> u bits 3..0 ; q4 -> float2 component ;
//            q5..q9 -> lane bits 4..0.
// 2 elements per wave (lane bit 5), 8 per 256-thread block.
//
// vs round 9 (VALU-saturated at 96-101%): packed fp32 math (v_pk_fma_f32)
// halves the q0..q4 + q5/q7 math streams; normalization deferred to the
// final store (circuit is linear). Gate order / bperm maps unchanged.

typedef float v2f __attribute__((ext_vector_type(2)));

// ---- cross-lane helpers -------------------------------------------------
template<int CTRL>
__device__ __forceinline__ float dpp_mov(float x) {
  int i = __builtin_bit_cast(int, x);
  i = __builtin_amdgcn_update_dpp(i, i, CTRL, 0xf, 0xf, true);
  return __builtin_bit_cast(float, i);
}
__device__ __forceinline__ float xl1(float x) { return dpp_mov<0xB1>(x); }   // lane^1
__device__ __forceinline__ float xl2(float x) { return dpp_mov<0x4E>(x); }   // lane^2
__device__ __forceinline__ float xl8(float x) { return dpp_mov<0x128>(x); }  // row_ror:8 == lane^8
template<int PAT>
__device__ __forceinline__ float swz(float x) {  // ds_swizzle BitMode
  int i = __builtin_amdgcn_ds_swizzle(__builtin_bit_cast(int, x), PAT);
  return __builtin_bit_cast(float, i);
}
__device__ __forceinline__ float xl4(float x)  { return swz<0x101F>(x); }    // lane^4
__device__ __forceinline__ float xl16(float x) { return swz<0x401F>(x); }    // lane^16
__device__ __forceinline__ float bperm(int addr, float x) {
  int i = __builtin_amdgcn_ds_bpermute(addr, __builtin_bit_cast(int, x));
  return __builtin_bit_cast(float, i);
}
__device__ __forceinline__ float red32(float x) {
  x += xl1(x); x += xl2(x); x += xl4(x); x += xl8(x); x += xl16(x); return x;
}

// ---- one level of the sum/diff tree -------------------------------------
template<int L2>
__device__ __forceinline__ float tree_level(float* t) {
  float a = 0.f, b = 0.f;
  #pragma unroll
  for (int j = 0; j < L2; ++j) {
    float e = t[2 * j], o = t[2 * j + 1];
    if (j & 1) b += e - o; else a += e - o;
    t[j] = e + o;
  }
  return a + b;
}

__global__ __launch_bounds__(256, 6) void circuit_kernel(
    const float* __restrict__ x, const float* __restrict__ params,
    float* __restrict__ out) {
  __shared__ float csh[160];  // cos/sin of pi*tanh(param)/2, [l*20 + 2q {+1}]

  const int tid  = threadIdx.x;
  const int wv   = tid >> 6;
  const int lane = tid & 63;
  const int h    = lane >> 5;   // element within wave (0..1)
  const int l5   = lane & 31;   // lane within group = index bits [4:0]
  const long elem = (long)blockIdx.x * 8 + wv * 2 + h;

  if (tid < 80) {
    float th = 1.57079632679489662f * tanhf(params[tid]);  // (pi*tanh)/2
    csh[2 * tid]     = cosf(th);
    csh[2 * tid + 1] = sinf(th);
  }

  // bpermute pull map (inverse of push (4,5),(6,7),(8,9),(5,6),(7,8)):
  //   m = l5; b1^=b2; b3^=b4; b0^=b1; b2^=b3; [odd scalar: b4^=1]
  int m = l5 ^ ((l5 & 4) >> 1);   // undo (7,8)
  m ^= (m & 16) >> 1;             // undo (5,6)
  m ^= (m & 2) >> 1;              // undo (8,9)
  m ^= (m & 8) >> 1;              // undo (6,7)
  const int addrE = ((lane & 32) | m) << 2;  // even scalar (.x) source
  const int addrO = addrE ^ 64;              // odd scalar (.y): lane b4 flips

  // ---- load: scalar s at x[s*32 + l5]; s = 2u (+1 for .y) ----------------
  v2f w[16];
  const float* xb = x + elem * 784 + l5;
  #pragma unroll
  for (int u = 0; u < 12; ++u) {
    w[u].x = xb[u * 64];
    w[u].y = xb[u * 64 + 32];
  }
  w[12].x = (l5 < 16) ? xb[768] : 0.f;
  w[12].y = 0.f;
  #pragma unroll
  for (int u = 13; u < 16; ++u) w[u] = (v2f){0.f, 0.f};

  // ---- norm^2 only (normalization deferred to the store) -----------------
  v2f acc = {0.f, 0.f};
  #pragma unroll
  for (int u = 0; u < 13; ++u) acc += w[u] * w[u];
  float nn  = red32(acc.x + acc.y);
  float inv = 1.0f / nn;

  __syncthreads();   // csh ready

  // ---- 8 layers, fully unrolled ------------------------------------------
  #pragma unroll
  for (int l = 0; l < 8; ++l) {
    const float* cl = &csh[l * 20];

    // 1. reg swaps for CNOT (0,1),(2,3)  [renames]
    #pragma unroll
    for (int u = 0; u < 16; ++u) if ((u & 12) == 8) { v2f t = w[u]; w[u] = w[u + 4]; w[u + 4] = t; } // (0,1)
    #pragma unroll
    for (int u = 0; u < 16; ++u) if ((u & 3) == 2) { v2f t = w[u]; w[u] = w[u + 1]; w[u + 1] = t; }  // (2,3)

    // 2. fused cross-lane CNOTs (4,5),(6,7),(8,9),(5,6),(7,8)
    #pragma unroll
    for (int u = 0; u < 16; ++u) {
      w[u].x = bperm(addrE, w[u].x);
      w[u].y = bperm(addrO, w[u].y);
    }

    // 3. reg swaps for CNOT (1,2); (3,4) = component swap for odd u
    #pragma unroll
    for (int u = 0; u < 16; ++u) if ((u & 6) == 4) { v2f t = w[u]; w[u] = w[u + 2]; w[u + 2] = t; }  // (1,2)
    #pragma unroll
    for (int u = 1; u < 16; u += 2) w[u] = __builtin_shufflevector(w[u], w[u], 1, 0);                // (3,4)

    // 4. RY q0..q3 (packed pair rotations over u-bits 3..0)
    { v2f cc = {cl[0], cl[0]}, ss = {cl[1], cl[1]};
      #pragma unroll
      for (int u = 0; u < 16; ++u) if ((u & 8) == 0) {
        v2f a = w[u], b = w[u + 8];
        w[u] = cc * a - ss * b;  w[u + 8] = ss * a + cc * b;
      } }
    { v2f cc = {cl[2], cl[2]}, ss = {cl[3], cl[3]};
      #pragma unroll
      for (int u = 0; u < 16; ++u) if ((u & 4) == 0) {
        v2f a = w[u], b = w[u + 4];
        w[u] = cc * a - ss * b;  w[u + 4] = ss * a + cc * b;
      } }
    { v2f cc = {cl[4], cl[4]}, ss = {cl[5], cl[5]};
      #pragma unroll
      for (int u = 0; u < 16; ++u) if ((u & 2) == 0) {
        v2f a = w[u], b = w[u + 2];
        w[u] = cc * a - ss * b;  w[u + 2] = ss * a + cc * b;
      } }
    { v2f cc = {cl[6], cl[6]}, ss = {cl[7], cl[7]};
      #pragma unroll
      for (int u = 0; u < 16; ++u) if ((u & 1) == 0) {
        v2f a = w[u], b = w[u + 1];
        w[u] = cc * a - ss * b;  w[u + 1] = ss * a + cc * b;
      } }

    // RY q4 (component pair): w' = (c,s)*w.xx + (-s,c)*w.yy
    { v2f A = {cl[8], cl[9]}, B = {-cl[9], cl[8]};
      #pragma unroll
      for (int u = 0; u < 16; ++u) {
        v2f xx = __builtin_shufflevector(w[u], w[u], 0, 0);
        v2f yy = __builtin_shufflevector(w[u], w[u], 1, 1);
        w[u] = A * xx + B * yy;
      } }

    // RY q5 (lane b4, ds_swizzle xor16)
    { float sn = (lane & 16) ? cl[11] : -cl[11];
      v2f cc = {cl[10], cl[10]}, ssn = {sn, sn};
      #pragma unroll
      for (int u = 0; u < 16; ++u) {
        v2f p = { xl16(w[u].x), xl16(w[u].y) };
        w[u] = cc * w[u] + ssn * p;
      } }
    // RY q6 (lane b3, DPP row_ror:8)
    { float sn = (lane & 8) ? cl[13] : -cl[13];
      v2f cc = {cl[12], cl[12]}, ssn = {sn, sn};
      #pragma unroll
      for (int u = 0; u < 16; ++u) {
        v2f p = { xl8(w[u].x), xl8(w[u].y) };
        w[u] = cc * w[u] + ssn * p;
      } }
    // RY q7 (lane b2, ds_swizzle xor4)
    { float sn = (lane & 4) ? cl[15] : -cl[15];
      v2f cc = {cl[14], cl[14]}, ssn = {sn, sn};
      #pragma unroll
      for (int u = 0; u < 16; ++u) {
        v2f p = { xl4(w[u].x), xl4(w[u].y) };
        w[u] = cc * w[u] + ssn * p;
      } }
    // RY q8 (lane b1, DPP xor2)
    { float sn = (lane & 2) ? cl[17] : -cl[17];
      v2f cc = {cl[16], cl[16]}, ssn = {sn, sn};
      #pragma unroll
      for (int u = 0; u < 16; ++u) {
        v2f p = { xl2(w[u].x), xl2(w[u].y) };
        w[u] = cc * w[u] + ssn * p;
      } }
    // RY q9 (lane b0, DPP xor1)
    { float sn = (lane & 1) ? cl[19] : -cl[19];
      v2f cc = {cl[18], cl[18]}, ssn = {sn, sn};
      #pragma unroll
      for (int u = 0; u < 16; ++u) {
        v2f p = { xl1(w[u].x), xl1(w[u].y) };
        w[u] = cc * w[u] + ssn * p;
      } }
  }

  // ---- expectation values (unnormalized; scaled by inv at the store) -----
  #pragma unroll
  for (int u = 0; u < 16; ++u) w[u] *= w[u];   // probabilities * nn

  float t16[16];
  float a0 = 0.f, a1 = 0.f;
  #pragma unroll
  for (int u = 0; u < 16; ++u) {
    float d = w[u].x - w[u].y;
    if (u & 1) a1 += d; else a0 += d;
    t16[u] = w[u].x + w[u].y;
  }
  float z[10];
  z[4] = red32(a0 + a1);
  z[3] = red32(tree_level<8>(t16));
  z[2] = red32(tree_level<4>(t16));
  z[1] = red32(tree_level<2>(t16));
  z[0] = red32(tree_level<1>(t16));
  float W = t16[0];  // per-lane total (unnormalized) probability
  // lane-bit qubits: signed reductions over the 32-lane group
  { float u = W + xl1(W); u += xl2(u); u += xl4(u); u += xl8(u);  float t = u - xl16(u); z[5] = (lane & 16) ? -t : t; }
  { float u = W + xl1(W); u += xl2(u); u += xl4(u); u += xl16(u); float t = u - xl8(u);  z[6] = (lane & 8)  ? -t : t; }
  { float u = W + xl1(W); u += xl2(u); u += xl8(u); u += xl16(u); float t = u - xl4(u);  z[7] = (lane & 4)  ? -t : t; }
  { float u = W + xl1(W); u += xl4(u); u += xl8(u); u += xl16(u); float t = u - xl2(u);  z[8] = (lane & 2)  ? -t : t; }
  { float u = W + xl2(W); u += xl4(u); u += xl8(u); u += xl16(u); float t = u - xl1(u);  z[9] = (lane & 1)  ? -t : t; }

  // ---- store: lane l5 (<10) writes column l5, normalized -----------------
  float o = z[0];
  #pragma unroll
  for (int j = 1; j < 10; ++j) o = (l5 == j) ? z[j] : o;
  if (l5 < 10) out[elem * 10 + l5] = o * inv;
}

extern "C" void kernel_launch(void* const* d_in, const int* in_sizes, int n_in,
                              void* d_out, int out_size, void* d_ws, size_t ws_size,
                              hipStream_t stream) {
  const float* x      = (const float*)d_in[0];   // [16384, 784]
  const float* params = (const float*)d_in[1];   // [8, 10]
  float* out          = (float*)d_out;           // [16384, 10]
  (void)d_ws; (void)ws_size; (void)in_sizes; (void)n_in; (void)out_size;
  // 16384 elements / 8 per block (2 per wave x 4 waves)
  circuit_kernel<<<2048, 256, 0, stream>>>(x, params, out);
}